// Round 2
// 160.334 us; speedup vs baseline: 1.0024x; 1.0024x over previous
//
#include <hip/hip_runtime.h>
#include <cstdint>
#include <cstddef>

// Problem constants (from reference setup_inputs)
#define BB 16
#define CC 7
#define HH 368
#define WW 640
#define LL (HH * WW)            // 235520 pixels per batch
#define NCLS 6                  // classes 1..6 (background 0 skipped)
#define NCOMBO (BB * NCLS)      // 96
#define PAIRS_PB (HH / 2)       // 184 row-pairs per batch
#define NPAIRS (BB * PAIRS_PB)  // 2944 row-pair jobs (1 wave each)
#define NBLK (NPAIRS / 4)       // 736 blocks of 4 waves

typedef float v4f __attribute__((ext_vector_type(4)));

__device__ inline v4f ntload4(const float* p) {
    return __builtin_nontemporal_load(reinterpret_cast<const v4f*>(p));
}

// Ordered-combine monoid over masked-pixel runs. A record covers a contiguous
// row range: S = sum of |d_i - d_prev| inside the range (telescoped per row),
// cnt = #masked px, first/last = d at first/last masked px. Bridging adds
// |B.first - A.last| when both sides non-empty. Associative; identity = cnt 0.
struct St { int S, cnt, first, last; };

__device__ inline St comb(const St& a, const St& b) {
    St r;
    int both = (a.cnt > 0) & (b.cnt > 0);
    r.S     = a.S + b.S + (both ? abs(b.first - a.last) : 0);
    r.cnt   = a.cnt + b.cnt;
    r.first = (a.cnt > 0) ? a.first : b.first;
    r.last  = (b.cnt > 0) ? b.last : a.last;
    return r;
}

__device__ inline St shfl_down_st(const St& s, int off) {
    St r;
    r.S     = __shfl_down(s.S, off, 64);
    r.cnt   = __shfl_down(s.cnt, off, 64);
    r.first = __shfl_down(s.first, off, 64);
    r.last  = __shfl_down(s.last, off, 64);
    return r;
}

// ---------------------------------------------------------------------------
// Kernel 1 (rowstat): softmax -> floor -> per-(row,class) commutative stats.
// One WAVE owns TWO consecutive rows (1280 px); per channel 5 back-to-back
// 1-KB wave bursts (5-KB contiguous span). R10 changes vs R9:
//   * explicit channel double-buffer: channel c+1's 5 loads are issued
//     before channel c's exp/acc compute (compiler-independent pipelining)
//   * lane 0 applies the comb monoid across the row pair and stores ONE
//     pair-record per class (halves kernel-2 input; 6 stores not 12)
//   * block 0 zeroes `out` (drops the hipMemsetAsync dispatch; stream order
//     puts this before combine_kernel's atomics)
// d = col - row telescopes within a row (S_row = mx - mn), so per-row stats
// are COMMUTATIVE min/max/sum -- plain shfl reduce (verified R7/R8, absmax
// 0.0). No LDS, no barriers. nt loads: logits consumed exactly once.
// Output: pairStats[(b*6+cls)*184 + pidx] = int4(S, cnt, first_d, last_d).
// ---------------------------------------------------------------------------
__global__ __launch_bounds__(256) void rowstat_kernel(const float* __restrict__ logits,
                                                      int4* __restrict__ pairStats,
                                                      float* __restrict__ out,
                                                      int out_n) {
    if (blockIdx.x == 0 && threadIdx.x == 0) {
        int n = out_n < 4 ? out_n : 4;                   // out is 1 float here
        for (int i = 0; i < n; ++i) out[i] = 0.0f;       // replaces memset node
    }

    int t     = threadIdx.x;
    int w     = t >> 6;
    int lane  = t & 63;
    int grow2 = blockIdx.x * 4 + w;        // row-pair id 0..2943
    int b  = grow2 / PAIRS_PB;
    int pidx = grow2 - b * PAIRS_PB;       // pair index within batch
    int r0 = pidx * 2;                     // first row of the pair
    const float* pairbase = logits + (size_t)b * CC * LL + (size_t)r0 * WW;

    // (s, w) accumulators for this thread's 20 pixels (5 chunks x 4 px).
    float sacc[20], wacc[20];
#pragma unroll
    for (int k = 0; k < 20; ++k) { sacc[k] = 0.0f; wacc[k] = 0.0f; }

    // Channel double-buffer: va = current channel's 5 bursts, vb = next.
    v4f va[5], vb[5];
#pragma unroll
    for (int it = 0; it < 5; ++it)
        va[it] = ntload4(pairbase + it * 256 + lane * 4);

#pragma unroll
    for (int c = 0; c < CC; ++c) {
        if (c + 1 < CC) {
            const float* pn = pairbase + (size_t)(c + 1) * LL;
#pragma unroll
            for (int it = 0; it < 5; ++it)     // issue next channel's bursts
                vb[it] = ntload4(pn + it * 256 + lane * 4);
        }
        float fc = (float)c;
#pragma unroll
        for (int it = 0; it < 5; ++it) {
            float e0 = __expf(va[it].x), e1 = __expf(va[it].y);
            float e2 = __expf(va[it].z), e3 = __expf(va[it].w);
            sacc[it * 4 + 0] += e0; wacc[it * 4 + 0] += e0 * fc;
            sacc[it * 4 + 1] += e1; wacc[it * 4 + 1] += e1 * fc;
            sacc[it * 4 + 2] += e2; wacc[it * 4 + 2] += e2 * fc;
            sacc[it * 4 + 3] += e3; wacc[it * 4 + 3] += e3 * fc;
        }
#pragma unroll
        for (int it = 0; it < 5; ++it) va[it] = vb[it];  // renamed away by unroll
    }

    // Per-(class, row-of-pair) stats. Chunks it=0,1 wholly row 0; it=3,4
    // wholly row 1; it=2 lane-split (compile-time specialization).
    int cnt[NCLS][2], mn[NCLS][2], mx[NCLS][2];
#pragma unroll
    for (int c = 0; c < NCLS; ++c)
#pragma unroll
        for (int R = 0; R < 2; ++R) { cnt[c][R] = 0; mn[c][R] = 1 << 30; mx[c][R] = -1; }

#pragma unroll
    for (int it = 0; it < 5; ++it) {
#pragma unroll
        for (int k = 0; k < 4; ++k) {
            int idx = it * 4 + k;
            int sv  = (int)floorf(__fdividef(wacc[idx], sacc[idx]));
            int px  = it * 256 + lane * 4 + k;   // 0..1279 within the pair
            if (it < 2) {                        // wholly row 0
                int col = px;
#pragma unroll
                for (int c = 0; c < NCLS; ++c) {
                    int m = (sv == c + 1);
                    cnt[c][0] += m;
                    mn[c][0] = m ? min(mn[c][0], col) : mn[c][0];
                    mx[c][0] = m ? max(mx[c][0], col) : mx[c][0];
                }
            } else if (it > 2) {                 // wholly row 1
                int col = px - WW;
#pragma unroll
                for (int c = 0; c < NCLS; ++c) {
                    int m = (sv == c + 1);
                    cnt[c][1] += m;
                    mn[c][1] = m ? min(mn[c][1], col) : mn[c][1];
                    mx[c][1] = m ? max(mx[c][1], col) : mx[c][1];
                }
            } else {                             // it == 2: lane-split
                int pr  = px >= WW;
                int col = pr ? (px - WW) : px;
#pragma unroll
                for (int c = 0; c < NCLS; ++c) {
                    int m  = (sv == c + 1);
                    int m0 = m & (pr == 0), m1 = m & pr;
                    cnt[c][0] += m0;
                    mn[c][0] = m0 ? min(mn[c][0], col) : mn[c][0];
                    mx[c][0] = m0 ? max(mx[c][0], col) : mx[c][0];
                    cnt[c][1] += m1;
                    mn[c][1] = m1 ? min(mn[c][1], col) : mn[c][1];
                    mx[c][1] = m1 ? max(mx[c][1], col) : mx[c][1];
                }
            }
        }
    }

    // Commutative wave reduce per (class,row); ballot-skip absent sets.
#pragma unroll
    for (int c = 0; c < NCLS; ++c) {
#pragma unroll
        for (int R = 0; R < 2; ++R) {
            if (__ballot(cnt[c][R] > 0) == 0ull) { cnt[c][R] = 0; continue; }
#pragma unroll
            for (int off = 1; off < 64; off <<= 1) {
                cnt[c][R] += __shfl_down(cnt[c][R], off, 64);
                mn[c][R]  = min(mn[c][R], __shfl_down(mn[c][R], off, 64));
                mx[c][R]  = max(mx[c][R], __shfl_down(mx[c][R], off, 64));
            }
        }
    }

    // Lane 0: fold the two row records into ONE pair record per class.
    if (lane == 0) {
#pragma unroll
        for (int c = 0; c < NCLS; ++c) {
            St pa{0, 0, 0, 0};
            if (cnt[c][0] > 0) {
                pa.S = mx[c][0] - mn[c][0]; pa.cnt = cnt[c][0];
                pa.first = mn[c][0] - r0;   pa.last = mx[c][0] - r0;
            }
            if (cnt[c][1] > 0) {
                St pb;
                pb.S = mx[c][1] - mn[c][1]; pb.cnt = cnt[c][1];
                pb.first = mn[c][1] - (r0 + 1); pb.last = mx[c][1] - (r0 + 1);
                pa = comb(pa, pb);
            }
            pairStats[(size_t)(b * NCLS + c) * PAIRS_PB + pidx] =
                make_int4(pa.S, pa.cnt, pa.first, pa.last);
        }
    }
}

// ---------------------------------------------------------------------------
// Kernel 2: per (batch,class) ordered combine of the 184 pair-records.
// One full wave per combo (24 blocks x 4 waves = 96 combos); lane l folds
// records [3l, 3l+3) left-to-right, then an order-preserving shfl_down tree
// (comb is associative) folds across lanes. No LDS, no barriers.
// atomicAdd into out[0] (zeroed by rowstat block 0, stream-ordered before us).
// ---------------------------------------------------------------------------
__global__ __launch_bounds__(256) void combine_kernel(const int4* __restrict__ pairStats,
                                                      float* __restrict__ out) {
    int t    = threadIdx.x;
    int wave = t >> 6;
    int lane = t & 63;
    int combo = blockIdx.x * 4 + wave;     // = b*NCLS + cls-1
    const int4* rp = pairStats + (size_t)combo * PAIRS_PB;

    St st{0, 0, 0, 0};
#pragma unroll
    for (int q = 0; q < 3; ++q) {
        int idx = lane * 3 + q;
        if (idx < PAIRS_PB) {
            int4 v = rp[idx];
            if (v.y > 0) {                 // (S, cnt, first, last)
                St rs{v.x, v.y, v.z, v.w};
                st = comb(st, rs);
            }
        }
    }

#pragma unroll
    for (int off = 1; off < 64; off <<= 1) {
        St o = shfl_down_st(st, off);
        st = comb(st, o);
    }

    if (lane == 0) {
        int n = st.cnt;
        if (n >= 2) {
            // npairs = n-1; mean = S/npairs; contribution = mean/(n+1)
            double res = ((double)st.S / (double)(n - 1)) / (double)(n + 1);
            atomicAdd(out, (float)res);
        }
    }
}

extern "C" void kernel_launch(void* const* d_in, const int* in_sizes, int n_in,
                              void* d_out, int out_size, void* d_ws, size_t ws_size,
                              hipStream_t stream) {
    const float* logits = (const float*)d_in[0];
    // d_in[1] (labels) is unused by the reference computation.
    float* out = (float*)d_out;

    int4* pairStats = (int4*)d_ws;         // 96 * 184 * 16 = 282,624 B

    // No memset dispatch: rowstat block 0 zeroes d_out (re-poisoned to 0xAA
    // before every replay), stream-ordered ahead of combine's atomics.
    rowstat_kernel<<<NBLK, 256, 0, stream>>>(logits, pairStats, out, out_size);
    combine_kernel<<<NCOMBO / 4, 256, 0, stream>>>(pairStats, out);
}